// Round 1
// baseline (9525.395 us; speedup 1.0000x reference)
//
#include <hip/hip_runtime.h>

#define N_NODES 100000
#define N_EDGES 1600000
#define N_GRAPHS 64
#define HDIM 150
#define PASSES 4

// ---------------- CSR build ----------------
__global__ void hist_kernel(const int* __restrict__ dst, int* __restrict__ counts, int n) {
  int i = blockIdx.x * blockDim.x + threadIdx.x;
  if (i < n) atomicAdd(&counts[dst[i]], 1);
}

__global__ __launch_bounds__(1024) void scan_kernel(const int* __restrict__ counts,
    int* __restrict__ row_start, int* __restrict__ cursor, int n) {
  __shared__ int sums[1024];
  int t = threadIdx.x;
  const int C = (n + 1023) >> 10;  // 98 elements per thread
  int b = t * C, e = min(b + C, n);
  int s = 0;
  for (int i = b; i < e; ++i) s += counts[i];
  sums[t] = s;
  __syncthreads();
  for (int off = 1; off < 1024; off <<= 1) {
    int v = 0;
    if (t >= off) v = sums[t - off];
    __syncthreads();
    if (t >= off) sums[t] += v;
    __syncthreads();
  }
  int pre = (t == 0) ? 0 : sums[t - 1];
  for (int i = b; i < e; ++i) {
    row_start[i] = pre; cursor[i] = pre; pre += counts[i];
  }
  if (t == 1023) row_start[n] = pre;  // total = N_EDGES
}

__global__ void fill_kernel(const int* __restrict__ src, const int* __restrict__ dst,
                            int* __restrict__ cursor, int* __restrict__ csr_src, int n) {
  int i = blockIdx.x * blockDim.x + threadIdx.x;
  if (i < n) {
    int pos = atomicAdd(&cursor[dst[i]], 1);
    csr_src[pos] = src[i];
  }
}

// ---------------- per-pass: incoming[v] = sum over edges u->v of h[u] ----------------
__global__ __launch_bounds__(256) void segsum_kernel(const float* __restrict__ h,
    const int* __restrict__ row_start, const int* __restrict__ csr_src,
    float* __restrict__ incoming) {
  int node = blockIdx.x * 4 + (threadIdx.x >> 6);  // one wave per node
  if (node >= N_NODES) return;
  int lane = threadIdx.x & 63;
  int b = row_start[node], e = row_start[node + 1];
  float a0 = 0.f, a1 = 0.f, a2 = 0.f;
  for (int j = b; j < e; ++j) {
    int s = csr_src[j];
    const float* hr = h + s * HDIM;
    a0 += hr[lane];
    a1 += hr[lane + 64];
    if (lane < HDIM - 128) a2 += hr[lane + 128];
  }
  float* out = incoming + node * HDIM;
  out[lane] = a0;
  out[lane + 64] = a1;
  if (lane < HDIM - 128) out[lane + 128] = a2;
}

// ---------------- fused GRU cell ----------------
// Tile: 128 nodes x 32 dims per block; 256 threads; per-thread 4m x 4d x 6 gates.
// LDS: Xs (incoming & h, k-chunked) + Ws (6 weight-row groups, k-chunked).
// m rows strided by 32 and d strided by 8 so wave LDS reads hit distinct banks.
#define MT 128
#define DT 32
#define KC 32
#define XPAD 36

__global__ __launch_bounds__(256) void gru_kernel(
    const float* __restrict__ xinc, const float* __restrict__ hcur,
    const float* __restrict__ wih, const float* __restrict__ whh,
    const float* __restrict__ bih, const float* __restrict__ bhh,
    float* __restrict__ hnext) {
  __shared__ __align__(16) float Xs[2][MT][XPAD];   // [mat][m][k]
  __shared__ __align__(16) float Ws[2][96][XPAD];   // [mat][g*32+dloc][k]
  const int dbase = blockIdx.x * DT;
  const int mbase = blockIdx.y * MT;
  const int tid = threadIdx.x;
  const int tx = tid & 7;    // d = dbase + tx + 8*di
  const int ty = tid >> 3;   // m = mbase + ty + 32*mi

  float acc[6][4][4];  // [gate][mi][di]: 0 ir, 1 iz, 2 in, 3 hr, 4 hz, 5 hn
#pragma unroll
  for (int a = 0; a < 6; ++a)
#pragma unroll
    for (int b = 0; b < 4; ++b)
#pragma unroll
      for (int c = 0; c < 4; ++c) acc[a][b][c] = 0.f;

  for (int kc = 0; kc < HDIM; kc += KC) {
    // stage X: 2 * 128 * 32 = 8192 elems, 32 per thread (coalesced k-fastest)
#pragma unroll
    for (int it = 0; it < (2 * MT * KC) / 256; ++it) {
      int idx = it * 256 + tid;
      int mat = idx >> 12;           // MT*KC = 4096
      int rem = idx & 4095;
      int m = rem >> 5, k = rem & 31;
      int gm = mbase + m, gk = kc + k;
      float v = 0.f;
      if (gm < N_NODES && gk < HDIM) v = (mat ? hcur : xinc)[gm * HDIM + gk];
      Xs[mat][m][k] = v;
    }
    // stage W: 2 * 96 * 32 = 6144 elems, 24 per thread
#pragma unroll
    for (int it = 0; it < (2 * 96 * KC) / 256; ++it) {
      int idx = it * 256 + tid;
      int mat = (idx >= 96 * KC) ? 1 : 0;
      int rem = idx - mat * (96 * KC);
      int r = rem >> 5, k = rem & 31;
      int g = r >> 5, dl = r & 31;
      int d = dbase + dl, gk = kc + k;
      float v = 0.f;
      if (d < HDIM && gk < HDIM) v = (mat ? whh : wih)[(d + g * HDIM) * HDIM + gk];
      Ws[mat][r][k] = v;
    }
    __syncthreads();
#pragma unroll
    for (int k0 = 0; k0 < KC; k0 += 4) {
      float4 xi[4], xh[4];
#pragma unroll
      for (int mi = 0; mi < 4; ++mi) {
        xi[mi] = *(const float4*)&Xs[0][ty + 32 * mi][k0];
        xh[mi] = *(const float4*)&Xs[1][ty + 32 * mi][k0];
      }
#pragma unroll
      for (int g = 0; g < 3; ++g) {
#pragma unroll
        for (int di = 0; di < 4; ++di) {
          const int r = (g << 5) + tx + (di << 3);
          float4 wi = *(const float4*)&Ws[0][r][k0];
          float4 wh = *(const float4*)&Ws[1][r][k0];
#pragma unroll
          for (int mi = 0; mi < 4; ++mi) {
            acc[g][mi][di]     += xi[mi].x * wi.x + xi[mi].y * wi.y + xi[mi].z * wi.z + xi[mi].w * wi.w;
            acc[3 + g][mi][di] += xh[mi].x * wh.x + xh[mi].y * wh.y + xh[mi].z * wh.z + xh[mi].w * wh.w;
          }
        }
      }
    }
    __syncthreads();
  }

  // epilogue: gates + state update (torch GRUCell semantics)
#pragma unroll
  for (int mi = 0; mi < 4; ++mi) {
    int gm = mbase + ty + 32 * mi;
    if (gm >= N_NODES) continue;
#pragma unroll
    for (int di = 0; di < 4; ++di) {
      int d = dbase + tx + (di << 3);
      if (d >= HDIM) continue;
      float ir = acc[0][mi][di] + bih[d];
      float iz = acc[1][mi][di] + bih[d + 150];
      float in_ = acc[2][mi][di] + bih[d + 300];
      float hr = acc[3][mi][di] + bhh[d];
      float hz = acc[4][mi][di] + bhh[d + 150];
      float hn = acc[5][mi][di] + bhh[d + 300];
      float r = 1.f / (1.f + __expf(-(ir + hr)));
      float z = 1.f / (1.f + __expf(-(iz + hz)));
      float narg = in_ + r * hn;
      float nn = 1.f - 2.f / (__expf(2.f * narg) + 1.f);  // tanh, overflow-safe
      float ho = hcur[gm * HDIM + d];
      hnext[gm * HDIM + d] = (1.f - z) * nn + z * ho;
    }
  }
}

// ---------------- readout ----------------
__global__ __launch_bounds__(64) void graph_accum_kernel(const float* __restrict__ h,
    const int* __restrict__ gids, float* __restrict__ gacc) {
  const int lane = threadIdx.x;
  const int nb = gridDim.x;
  int chunk = (N_NODES + nb - 1) / nb;
  int b = blockIdx.x * chunk, e = min(b + chunk, N_NODES);
  if (b >= e) return;
  float a0 = 0.f, a1 = 0.f, a2 = 0.f;
  int cur = gids[b];
  for (int i = b; i < e; ++i) {
    int gid = gids[i];  // sorted -> wave-uniform
    if (gid != cur) {
      atomicAdd(&gacc[cur * HDIM + lane], a0);
      atomicAdd(&gacc[cur * HDIM + lane + 64], a1);
      if (lane < HDIM - 128) atomicAdd(&gacc[cur * HDIM + lane + 128], a2);
      a0 = a1 = a2 = 0.f; cur = gid;
    }
    const float* hr = h + i * HDIM;
    a0 += hr[lane]; a1 += hr[lane + 64];
    if (lane < HDIM - 128) a2 += hr[lane + 128];
  }
  atomicAdd(&gacc[cur * HDIM + lane], a0);
  atomicAdd(&gacc[cur * HDIM + lane + 64], a1);
  if (lane < HDIM - 128) atomicAdd(&gacc[cur * HDIM + lane + 128], a2);
}

__global__ __launch_bounds__(192) void readout_kernel(const float* __restrict__ gacc,
    const float* __restrict__ fc1w, const float* __restrict__ fc1b,
    const float* __restrict__ fc2w, const float* __restrict__ fc2b,
    const float* __restrict__ fclw, const float* __restrict__ fclb,
    float* __restrict__ out) {
  __shared__ float x0[HDIM];
  __shared__ float y1[80];
  __shared__ float y2[80];
  int g = blockIdx.x, t = threadIdx.x;
  if (t < HDIM) {
    float v = logf(gacc[g * HDIM + t]);  // log(neg)=NaN, log(0)=-inf
    if (v != v) v = 0.f;                 // nan->0
    x0[t] = fmaxf(v, 0.f);               // relu (also clamps -inf)
  }
  __syncthreads();
  if (t < 80) {
    float s = fc1b[t];
    for (int k = 0; k < HDIM; ++k) s += x0[k] * fc1w[t * HDIM + k];
    y1[t] = (s > 0.f) ? s : 0.01f * s;   // leaky_relu
  }
  __syncthreads();
  if (t < 80) {
    float s = fc2b[t];
    for (int k = 0; k < 80; ++k) s += y1[k] * fc2w[t * 80 + k];
    y2[t] = (s > 0.f) ? s : 0.01f * s;
  }
  __syncthreads();
  if (t < 10) {
    float s = fclb[t];
    for (int k = 0; k < 80; ++k) s += y2[k] * fclw[t * 80 + k];
    out[g * 10 + t] = s;
  }
}

// ---------------- launch ----------------
extern "C" void kernel_launch(void* const* d_in, const int* in_sizes, int n_in,
                              void* d_out, int out_size, void* d_ws, size_t ws_size,
                              hipStream_t stream) {
  float* nodes = (float*)d_in[0];  // mutated; harness restores before every launch
  const int* src = (const int*)d_in[1];
  const int* dst = (const int*)d_in[2];
  const int* gids = (const int*)d_in[3];
  const float* wih = (const float*)d_in[4];
  const float* whh = (const float*)d_in[5];
  const float* bih = (const float*)d_in[6];
  const float* bhh = (const float*)d_in[7];
  const float* fc1w = (const float*)d_in[8];
  const float* fc1b = (const float*)d_in[9];
  const float* fc2w = (const float*)d_in[10];
  const float* fc2b = (const float*)d_in[11];
  const float* fclw = (const float*)d_in[12];
  const float* fclb = (const float*)d_in[13];
  float* out = (float*)d_out;

  // workspace carve (~128.5 MB total)
  char* wsp = (char*)d_ws;
  size_t off = 0;
  auto carve = [&](size_t bytes) {
    void* p = wsp + off;
    off += (bytes + 255) & ~(size_t)255;
    return p;
  };
  int* counts    = (int*)carve((size_t)N_NODES * 4);
  int* rowstart  = (int*)carve((size_t)(N_NODES + 1) * 4);
  int* cursor    = (int*)carve((size_t)N_NODES * 4);
  int* csr       = (int*)carve((size_t)N_EDGES * 4);
  float* incoming = (float*)carve((size_t)N_NODES * HDIM * 4);
  float* hA       = (float*)carve((size_t)N_NODES * HDIM * 4);
  float* gacc     = (float*)carve((size_t)N_GRAPHS * HDIM * 4);
  (void)ws_size; (void)in_sizes; (void)n_in; (void)out_size;

  hipMemsetAsync(counts, 0, (size_t)N_NODES * 4, stream);
  hipMemsetAsync(gacc, 0, (size_t)N_GRAPHS * HDIM * 4, stream);

  hist_kernel<<<(N_EDGES + 255) / 256, 256, 0, stream>>>(dst, counts, N_EDGES);
  scan_kernel<<<1, 1024, 0, stream>>>(counts, rowstart, cursor, N_NODES);
  fill_kernel<<<(N_EDGES + 255) / 256, 256, 0, stream>>>(src, dst, cursor, csr, N_EDGES);

  float* hcur = nodes;
  float* hnxt = hA;
  for (int p = 0; p < PASSES; ++p) {
    segsum_kernel<<<(N_NODES + 3) / 4, 256, 0, stream>>>(hcur, rowstart, csr, incoming);
    gru_kernel<<<dim3((HDIM + DT - 1) / DT, (N_NODES + MT - 1) / MT), 256, 0, stream>>>(
        incoming, hcur, wih, whh, bih, bhh, hnxt);
    float* tmp = hcur; hcur = hnxt; hnxt = tmp;
  }
  // PASSES even -> final h lives in the nodes buffer

  graph_accum_kernel<<<512, 64, 0, stream>>>(hcur, gids, gacc);
  readout_kernel<<<N_GRAPHS, 192, 0, stream>>>(gacc, fc1w, fc1b, fc2w, fc2b, fclw, fclb, out);
}

// Round 2
// 2200.533 us; speedup vs baseline: 4.3287x; 4.3287x over previous
//
#include <hip/hip_runtime.h>

#define N_NODES 100000
#define N_EDGES 1600000
#define N_GRAPHS 64
#define HDIM 150
#define PASSES 4
#define MROWS_PAD 100032   // 1563 * 64

typedef __attribute__((ext_vector_type(8))) short bf16x8;
typedef __attribute__((ext_vector_type(4))) float f32x4;

__device__ __forceinline__ ushort bf16_rne(float x) {
  uint u = __float_as_uint(x);
  u += 0x7FFFu + ((u >> 16) & 1u);
  return (ushort)(u >> 16);
}
__device__ __forceinline__ float bf16f(ushort h) { return __uint_as_float(((uint)h) << 16); }

// ---------------- CSR build ----------------
__global__ void hist_kernel(const int* __restrict__ dst, int* __restrict__ counts, int n) {
  int i = blockIdx.x * blockDim.x + threadIdx.x;
  if (i < n) atomicAdd(&counts[dst[i]], 1);
}

__global__ __launch_bounds__(1024) void scan_kernel(const int* __restrict__ counts,
    int* __restrict__ row_start, int* __restrict__ cursor, int n) {
  __shared__ int sums[1024];
  int t = threadIdx.x;
  const int C = (n + 1023) >> 10;
  int b = t * C, e = min(b + C, n);
  int s = 0;
  for (int i = b; i < e; ++i) s += counts[i];
  sums[t] = s;
  __syncthreads();
  for (int off = 1; off < 1024; off <<= 1) {
    int v = 0;
    if (t >= off) v = sums[t - off];
    __syncthreads();
    if (t >= off) sums[t] += v;
    __syncthreads();
  }
  int pre = (t == 0) ? 0 : sums[t - 1];
  for (int i = b; i < e; ++i) {
    row_start[i] = pre; cursor[i] = pre; pre += counts[i];
  }
  if (t == 1023) row_start[n] = pre;
}

__global__ void fill_kernel(const int* __restrict__ src, const int* __restrict__ dst,
                            int* __restrict__ cursor, int* __restrict__ csr_src, int n) {
  int i = blockIdx.x * blockDim.x + threadIdx.x;
  if (i < n) {
    int pos = atomicAdd(&cursor[dst[i]], 1);
    csr_src[pos] = src[i];
  }
}

// ---------------- weight split: Wcat[ch*160+dd][k], 960x160, bf16 hi/lo ----------------
__global__ void wbuild_kernel(const float* __restrict__ wih, const float* __restrict__ whh,
                              ushort* __restrict__ Whi, ushort* __restrict__ Wlo) {
  int idx = blockIdx.x * 256 + threadIdx.x;
  if (idx >= 960 * 160) return;
  int n = idx / 160, k = idx - n * 160;
  int ch = n / 160, dd = n - ch * 160;
  float v = 0.f;
  if (dd < HDIM && k < HDIM)
    v = (ch < 3) ? wih[(ch * HDIM + dd) * HDIM + k] : whh[((ch - 3) * HDIM + dd) * HDIM + k];
  ushort hi = bf16_rne(v);
  ushort lo = bf16_rne(v - bf16f(hi));
  Whi[idx] = hi; Wlo[idx] = lo;
}

// ---------------- h (fp32, [N,150]) -> hi/lo bf16 [MROWS_PAD,160] ----------------
__global__ __launch_bounds__(256) void hsplit_kernel(const float* __restrict__ h,
    ushort* __restrict__ Hhi, ushort* __restrict__ Hlo) {
  int node = blockIdx.x * 4 + (threadIdx.x >> 6);
  if (node >= N_NODES) return;
  int lane = threadIdx.x & 63;
  const float* hr = h + node * HDIM;
  float a0 = hr[lane], a1 = hr[lane + 64];
  float a2 = (lane < 22) ? hr[lane + 128] : 0.f;
  int base = node * 160;
  ushort h0 = bf16_rne(a0), l0 = bf16_rne(a0 - bf16f(h0));
  ushort h1 = bf16_rne(a1), l1 = bf16_rne(a1 - bf16f(h1));
  Hhi[base + lane] = h0; Hlo[base + lane] = l0;
  Hhi[base + 64 + lane] = h1; Hlo[base + 64 + lane] = l1;
  if (lane < 32) {
    ushort h2 = 0, l2 = 0;
    if (lane < 22) { h2 = bf16_rne(a2); l2 = bf16_rne(a2 - bf16f(h2)); }
    Hhi[base + 128 + lane] = h2; Hlo[base + 128 + lane] = l2;
  }
}

// ---------------- segment sum -> X hi/lo directly ----------------
__global__ __launch_bounds__(256) void segsum_kernel(const float* __restrict__ h,
    const int* __restrict__ row_start, const int* __restrict__ csr_src,
    ushort* __restrict__ Xhi, ushort* __restrict__ Xlo) {
  int node = blockIdx.x * 4 + (threadIdx.x >> 6);
  if (node >= N_NODES) return;
  int lane = threadIdx.x & 63;
  int b = row_start[node], e = row_start[node + 1];
  float a0 = 0.f, a1 = 0.f, a2 = 0.f;
  for (int j = b; j < e; ++j) {
    int s = csr_src[j];
    const float* hr = h + s * HDIM;
    a0 += hr[lane];
    a1 += hr[lane + 64];
    if (lane < 22) a2 += hr[lane + 128];
  }
  int base = node * 160;
  ushort h0 = bf16_rne(a0), l0 = bf16_rne(a0 - bf16f(h0));
  ushort h1 = bf16_rne(a1), l1 = bf16_rne(a1 - bf16f(h1));
  Xhi[base + lane] = h0; Xlo[base + lane] = l0;
  Xhi[base + 64 + lane] = h1; Xlo[base + 64 + lane] = l1;
  if (lane < 32) {
    ushort h2 = 0, l2 = 0;
    if (lane < 22) { h2 = bf16_rne(a2); l2 = bf16_rne(a2 - bf16f(h2)); }
    Xhi[base + 128 + lane] = h2; Xlo[base + 128 + lane] = l2;
  }
}

// ---------------- fused MFMA GRU ----------------
// Grid (5 dblk, 1563 mblk). Block: 256 thr = 4 waves.
// Wave 0: X-side, dt=0, ch{0,1,2}; wave 1: X dt=1; wave 2: H dt=0 ch{3,4,5}; wave 3: H dt=1.
// Each wave: 4 m-tiles (64 rows) x 3 n-tiles, split-bf16 -> 3 MFMA per pair.
// A staged to LDS (double-buffered 2x16KB), XOR-octet swizzle (2-way = free).
// Epilogue: H-waves publish accs via LDS; X-waves fuse gates + state update.
__global__ __launch_bounds__(256) void gru_mfma_kernel(
    const ushort* __restrict__ Xhi, const ushort* __restrict__ Xlo,
    const ushort* __restrict__ Hhi, const ushort* __restrict__ Hlo,
    const ushort* __restrict__ Whi, const ushort* __restrict__ Wlo,
    const float* __restrict__ bih, const float* __restrict__ bhh,
    const float* __restrict__ hcur, float* __restrict__ hnext) {
  __shared__ ushort smem[2][8192];  // 2 x 16KB k-buffers; reused as 24KB f32 in epilogue
  const int dblk = blockIdx.x;
  const int mblk = blockIdx.y;
  const int tid = threadIdx.x;
  const int w = tid >> 6;
  const int l = tid & 63;
  const int c16 = l & 15;
  const int koct = l >> 4;

  // staging map: thread -> (buf s, row sr, octet so); swizzled octet sop
  const int sr = tid >> 2;
  const int so = tid & 3;
  const int sop = so ^ ((sr >> 1) & 3);
  const int g_off = (mblk * 64 + sr) * 160 + so * 8;
  const ushort* sbase[4] = {Xhi, Xlo, Hhi, Hlo};
  const int lds_w_off = sr * 64 + sop * 16;  // + s*4096 + buf*16384

  const int hi_b = (w < 2) ? 0 : 2;
  const int dt = w & 1;
  const int ch0 = (w < 2) ? 0 : 3;
  const int nbase = dblk * 32 + dt * 16 + c16;

  f32x4 acc[3][4];
#pragma unroll
  for (int a = 0; a < 3; ++a)
#pragma unroll
    for (int b = 0; b < 4; ++b) acc[a][b] = (f32x4){0.f, 0.f, 0.f, 0.f};

  bf16x8 st[4];
#pragma unroll
  for (int s = 0; s < 4; ++s) st[s] = *(const bf16x8*)(sbase[s] + g_off);
#pragma unroll
  for (int s = 0; s < 4; ++s)
    *(bf16x8*)((char*)smem + s * 4096 + lds_w_off) = st[s];
  __syncthreads();

#pragma unroll
  for (int kc = 0; kc < 5; ++kc) {
    const int cur = kc & 1;
    if (kc < 4) {
#pragma unroll
      for (int s = 0; s < 4; ++s)
        st[s] = *(const bf16x8*)(sbase[s] + g_off + (kc + 1) * 32);
    }
    bf16x8 ahi[4], alo[4];
#pragma unroll
    for (int mt = 0; mt < 4; ++mt) {
      const int r = mt * 16 + c16;
      const int ob = (koct ^ ((r >> 1) & 3)) * 16;
      ahi[mt] = *(const bf16x8*)((char*)smem + cur * 16384 + hi_b * 4096 + r * 64 + ob);
      alo[mt] = *(const bf16x8*)((char*)smem + cur * 16384 + (hi_b + 1) * 4096 + r * 64 + ob);
    }
    bf16x8 bhi[3], blo[3];
#pragma unroll
    for (int cl = 0; cl < 3; ++cl) {
      const int wo = ((ch0 + cl) * 160 + nbase) * 160 + kc * 32 + koct * 8;
      bhi[cl] = *(const bf16x8*)(Whi + wo);
      blo[cl] = *(const bf16x8*)(Wlo + wo);
    }
    // product-major ordering: 12 independent MFMAs between same-acc repeats
#pragma unroll
    for (int cl = 0; cl < 3; ++cl)
#pragma unroll
      for (int mt = 0; mt < 4; ++mt)
        acc[cl][mt] = __builtin_amdgcn_mfma_f32_16x16x32_bf16(ahi[mt], bhi[cl], acc[cl][mt], 0, 0, 0);
#pragma unroll
    for (int cl = 0; cl < 3; ++cl)
#pragma unroll
      for (int mt = 0; mt < 4; ++mt)
        acc[cl][mt] = __builtin_amdgcn_mfma_f32_16x16x32_bf16(ahi[mt], blo[cl], acc[cl][mt], 0, 0, 0);
#pragma unroll
    for (int cl = 0; cl < 3; ++cl)
#pragma unroll
      for (int mt = 0; mt < 4; ++mt)
        acc[cl][mt] = __builtin_amdgcn_mfma_f32_16x16x32_bf16(alo[mt], bhi[cl], acc[cl][mt], 0, 0, 0);
    if (kc < 4) {
      const int nb = (kc + 1) & 1;
#pragma unroll
      for (int s = 0; s < 4; ++s)
        *(bf16x8*)((char*)smem + nb * 16384 + s * 4096 + lds_w_off) = st[s];
    }
    __syncthreads();
  }

  // epilogue: H-waves publish, X-waves combine
  float* eps = (float*)smem;
  if (w >= 2) {
    const int wi = w - 2;
#pragma unroll
    for (int cl = 0; cl < 3; ++cl)
#pragma unroll
      for (int mt = 0; mt < 4; ++mt)
        *(f32x4*)&eps[(((wi * 3 + cl) * 4 + mt) * 64 + l) * 4] = acc[cl][mt];
  }
  __syncthreads();
  if (w < 2) {
    const int d = dblk * 32 + dt * 16 + c16;
    if (d < HDIM) {
      const float bir = bih[d], biz = bih[HDIM + d], bin = bih[2 * HDIM + d];
      const float bhr = bhh[d], bhz = bhh[HDIM + d], bhn = bhh[2 * HDIM + d];
#pragma unroll
      for (int mt = 0; mt < 4; ++mt) {
        const int mb = mblk * 64 + mt * 16 + koct * 4;
        f32x4 hr4 = *(const f32x4*)&eps[(((dt * 3 + 0) * 4 + mt) * 64 + l) * 4];
        f32x4 hz4 = *(const f32x4*)&eps[(((dt * 3 + 1) * 4 + mt) * 64 + l) * 4];
        f32x4 hn4 = *(const f32x4*)&eps[(((dt * 3 + 2) * 4 + mt) * 64 + l) * 4];
#pragma unroll
        for (int j = 0; j < 4; ++j) {
          const int m = mb + j;
          if (m < N_NODES) {
            const float r = 1.f / (1.f + __expf(-(acc[0][mt][j] + bir + hr4[j] + bhr)));
            const float z = 1.f / (1.f + __expf(-(acc[1][mt][j] + biz + hz4[j] + bhz)));
            const float na = acc[2][mt][j] + bin + r * (hn4[j] + bhn);
            const float nn = 1.f - 2.f / (__expf(2.f * na) + 1.f);  // tanh
            const float ho = hcur[m * HDIM + d];
            hnext[m * HDIM + d] = (1.f - z) * nn + z * ho;
          }
        }
      }
    }
  }
}

// ---------------- readout ----------------
__global__ __launch_bounds__(64) void graph_accum_kernel(const float* __restrict__ h,
    const int* __restrict__ gids, float* __restrict__ gacc) {
  const int lane = threadIdx.x;
  const int nb = gridDim.x;
  int chunk = (N_NODES + nb - 1) / nb;
  int b = blockIdx.x * chunk, e = min(b + chunk, N_NODES);
  if (b >= e) return;
  float a0 = 0.f, a1 = 0.f, a2 = 0.f;
  int cur = gids[b];
  for (int i = b; i < e; ++i) {
    int gid = gids[i];
    if (gid != cur) {
      atomicAdd(&gacc[cur * HDIM + lane], a0);
      atomicAdd(&gacc[cur * HDIM + lane + 64], a1);
      if (lane < 22) atomicAdd(&gacc[cur * HDIM + lane + 128], a2);
      a0 = a1 = a2 = 0.f; cur = gid;
    }
    const float* hr = h + i * HDIM;
    a0 += hr[lane]; a1 += hr[lane + 64];
    if (lane < 22) a2 += hr[lane + 128];
  }
  atomicAdd(&gacc[cur * HDIM + lane], a0);
  atomicAdd(&gacc[cur * HDIM + lane + 64], a1);
  if (lane < 22) atomicAdd(&gacc[cur * HDIM + lane + 128], a2);
}

__global__ __launch_bounds__(192) void readout_kernel(const float* __restrict__ gacc,
    const float* __restrict__ fc1w, const float* __restrict__ fc1b,
    const float* __restrict__ fc2w, const float* __restrict__ fc2b,
    const float* __restrict__ fclw, const float* __restrict__ fclb,
    float* __restrict__ out) {
  __shared__ float x0[HDIM];
  __shared__ float y1[80];
  __shared__ float y2[80];
  int g = blockIdx.x, t = threadIdx.x;
  if (t < HDIM) {
    float v = logf(gacc[g * HDIM + t]);
    if (v != v) v = 0.f;
    x0[t] = fmaxf(v, 0.f);
  }
  __syncthreads();
  if (t < 80) {
    float s = fc1b[t];
    for (int k = 0; k < HDIM; ++k) s += x0[k] * fc1w[t * HDIM + k];
    y1[t] = (s > 0.f) ? s : 0.01f * s;
  }
  __syncthreads();
  if (t < 80) {
    float s = fc2b[t];
    for (int k = 0; k < 80; ++k) s += y1[k] * fc2w[t * 80 + k];
    y2[t] = (s > 0.f) ? s : 0.01f * s;
  }
  __syncthreads();
  if (t < 10) {
    float s = fclb[t];
    for (int k = 0; k < 80; ++k) s += y2[k] * fclw[t * 80 + k];
    out[g * 10 + t] = s;
  }
}

// ---------------- launch ----------------
extern "C" void kernel_launch(void* const* d_in, const int* in_sizes, int n_in,
                              void* d_out, int out_size, void* d_ws, size_t ws_size,
                              hipStream_t stream) {
  float* nodes = (float*)d_in[0];
  const int* src = (const int*)d_in[1];
  const int* dst = (const int*)d_in[2];
  const int* gids = (const int*)d_in[3];
  const float* wih = (const float*)d_in[4];
  const float* whh = (const float*)d_in[5];
  const float* bih = (const float*)d_in[6];
  const float* bhh = (const float*)d_in[7];
  const float* fc1w = (const float*)d_in[8];
  const float* fc1b = (const float*)d_in[9];
  const float* fc2w = (const float*)d_in[10];
  const float* fc2b = (const float*)d_in[11];
  const float* fclw = (const float*)d_in[12];
  const float* fclb = (const float*)d_in[13];
  float* out = (float*)d_out;

  char* wsp = (char*)d_ws;
  size_t off = 0;
  auto carve = [&](size_t bytes) {
    void* p = wsp + off;
    off += (bytes + 255) & ~(size_t)255;
    return p;
  };
  int* counts   = (int*)carve((size_t)N_NODES * 4);
  int* rowstart = (int*)carve((size_t)(N_NODES + 1) * 4);
  int* cursor   = (int*)carve((size_t)N_NODES * 4);
  int* csr      = (int*)carve((size_t)N_EDGES * 4);
  ushort* Xhi   = (ushort*)carve((size_t)MROWS_PAD * 160 * 2);
  ushort* Xlo   = (ushort*)carve((size_t)MROWS_PAD * 160 * 2);
  ushort* Hhi   = (ushort*)carve((size_t)MROWS_PAD * 160 * 2);
  ushort* Hlo   = (ushort*)carve((size_t)MROWS_PAD * 160 * 2);
  float* hA     = (float*)carve((size_t)N_NODES * HDIM * 4);
  ushort* Whi   = (ushort*)carve((size_t)960 * 160 * 2);
  ushort* Wlo   = (ushort*)carve((size_t)960 * 160 * 2);
  float* gacc   = (float*)carve((size_t)N_GRAPHS * HDIM * 4);
  (void)ws_size; (void)in_sizes; (void)n_in; (void)out_size;

  hipMemsetAsync(counts, 0, (size_t)N_NODES * 4, stream);
  hipMemsetAsync(gacc, 0, (size_t)N_GRAPHS * HDIM * 4, stream);

  hist_kernel<<<(N_EDGES + 255) / 256, 256, 0, stream>>>(dst, counts, N_EDGES);
  scan_kernel<<<1, 1024, 0, stream>>>(counts, rowstart, cursor, N_NODES);
  fill_kernel<<<(N_EDGES + 255) / 256, 256, 0, stream>>>(src, dst, cursor, csr, N_EDGES);
  wbuild_kernel<<<600, 256, 0, stream>>>(wih, whh, Whi, Wlo);
  hsplit_kernel<<<25000, 256, 0, stream>>>(nodes, Hhi, Hlo);

  float* hcur = nodes;
  float* hnxt = hA;
  for (int p = 0; p < PASSES; ++p) {
    segsum_kernel<<<25000, 256, 0, stream>>>(hcur, rowstart, csr, Xhi, Xlo);
    gru_mfma_kernel<<<dim3(5, 1563), 256, 0, stream>>>(
        Xhi, Xlo, Hhi, Hlo, Whi, Wlo, bih, bhh, hcur, hnxt);
    if (p < PASSES - 1)
      hsplit_kernel<<<25000, 256, 0, stream>>>(hnxt, Hhi, Hlo);
    float* tmp = hcur; hcur = hnxt; hnxt = tmp;
  }
  // PASSES even -> final h in nodes buffer

  graph_accum_kernel<<<512, 64, 0, stream>>>(hcur, gids, gacc);
  readout_kernel<<<N_GRAPHS, 192, 0, stream>>>(gacc, fc1w, fc1b, fc2w, fc2b, fclw, fclb, out);
}

// Round 4
// 1677.499 us; speedup vs baseline: 5.6783x; 1.3118x over previous
//
#include <hip/hip_runtime.h>

#define N_NODES 100000
#define N_EDGES 1600000
#define N_GRAPHS 64
#define HDIM 150
#define PASSES 4
#define MROWS_PAD 100032   // 1563 * 64
#define SCAN_NBLK 391      // ceil(100000/256)

typedef __attribute__((ext_vector_type(8))) short bf16x8;
typedef __attribute__((ext_vector_type(4))) float f32x4;

__device__ __forceinline__ ushort bf16_rne(float x) {
  uint u = __float_as_uint(x);
  u += 0x7FFFu + ((u >> 16) & 1u);
  return (ushort)(u >> 16);
}
__device__ __forceinline__ float bf16f(ushort h) { return __uint_as_float(((uint)h) << 16); }

// ---------------- CSR build ----------------
__global__ void hist_kernel(const int* __restrict__ dst, int* __restrict__ counts, int n) {
  int i = blockIdx.x * blockDim.x + threadIdx.x;
  if (i < n) atomicAdd(&counts[dst[i]], 1);
}

// multi-block scan: (1) block partial sums, (2) scan partials, (3) apply
__global__ __launch_bounds__(256) void scan1_kernel(const int* __restrict__ counts,
                                                    int* __restrict__ partials) {
  int i = blockIdx.x * 256 + threadIdx.x;
  int v = (i < N_NODES) ? counts[i] : 0;
#pragma unroll
  for (int o = 32; o; o >>= 1) v += __shfl_down(v, o);
  __shared__ int ws4[4];
  if ((threadIdx.x & 63) == 0) ws4[threadIdx.x >> 6] = v;
  __syncthreads();
  if (threadIdx.x == 0) partials[blockIdx.x] = ws4[0] + ws4[1] + ws4[2] + ws4[3];
}

__global__ __launch_bounds__(512) void scan2_kernel(int* __restrict__ partials,
                                                    int* __restrict__ row_start) {
  __shared__ int s[512];
  int t = threadIdx.x;
  int v = (t < SCAN_NBLK) ? partials[t] : 0;
  s[t] = v;
  __syncthreads();
  for (int o = 1; o < 512; o <<= 1) {
    int u = (t >= o) ? s[t - o] : 0;
    __syncthreads();
    s[t] += u;
    __syncthreads();
  }
  if (t < SCAN_NBLK) partials[t] = s[t] - v;  // exclusive block offsets
  if (t == 0) row_start[N_NODES] = s[511];    // total = N_EDGES
}

__global__ __launch_bounds__(256) void scan3_kernel(const int* __restrict__ counts,
    const int* __restrict__ partials, int* __restrict__ row_start, int* __restrict__ cursor) {
  __shared__ int s[256];
  int t = threadIdx.x, i = blockIdx.x * 256 + t;
  int v = (i < N_NODES) ? counts[i] : 0;
  s[t] = v;
  __syncthreads();
  for (int o = 1; o < 256; o <<= 1) {
    int u = (t >= o) ? s[t - o] : 0;
    __syncthreads();
    s[t] += u;
    __syncthreads();
  }
  if (i < N_NODES) {
    int ex = s[t] - v + partials[blockIdx.x];
    row_start[i] = ex; cursor[i] = ex;
  }
}

__global__ void fill_kernel(const int* __restrict__ src, const int* __restrict__ dst,
                            int* __restrict__ cursor, int* __restrict__ csr_src, int n) {
  int i = blockIdx.x * blockDim.x + threadIdx.x;
  if (i < n) {
    int pos = atomicAdd(&cursor[dst[i]], 1);
    csr_src[pos] = src[i];
  }
}

// ---------------- weight split: Wcat[ch*160+dd][k], 960x160, bf16 hi/lo ----------------
__global__ void wbuild_kernel(const float* __restrict__ wih, const float* __restrict__ whh,
                              ushort* __restrict__ Whi, ushort* __restrict__ Wlo) {
  int idx = blockIdx.x * 256 + threadIdx.x;
  if (idx >= 960 * 160) return;
  int n = idx / 160, k = idx - n * 160;
  int ch = n / 160, dd = n - ch * 160;
  float v = 0.f;
  if (dd < HDIM && k < HDIM)
    v = (ch < 3) ? wih[(ch * HDIM + dd) * HDIM + k] : whh[((ch - 3) * HDIM + dd) * HDIM + k];
  ushort hi = bf16_rne(v);
  ushort lo = bf16_rne(v - bf16f(hi));
  Whi[idx] = hi; Wlo[idx] = lo;
}

// ---------------- segment sum: X[v] = sum h[u] over edges u->v; writes bf16 hi/lo ----------------
__global__ __launch_bounds__(256) void segsum_kernel(const float* __restrict__ h, const int hstride,
    const int* __restrict__ row_start, const int* __restrict__ csr_src,
    ushort* __restrict__ Xhi, ushort* __restrict__ Xlo) {
  int node = blockIdx.x * 4 + (threadIdx.x >> 6);
  if (node >= N_NODES) return;
  int lane = threadIdx.x & 63;
  int b = row_start[node], e = row_start[node + 1];
  float a0 = 0.f, a1 = 0.f, a2 = 0.f;
  for (int j = b; j < e; ++j) {
    const float* hr = h + (size_t)csr_src[j] * hstride;
    a0 += hr[lane];
    a1 += hr[lane + 64];
    if (lane < 22) a2 += hr[lane + 128];
  }
  int base = node * 160;
  ushort h0 = bf16_rne(a0), l0 = bf16_rne(a0 - bf16f(h0));
  ushort h1 = bf16_rne(a1), l1 = bf16_rne(a1 - bf16f(h1));
  Xhi[base + lane] = h0; Xlo[base + lane] = l0;
  Xhi[base + 64 + lane] = h1; Xlo[base + 64 + lane] = l1;
  if (lane < 32) {
    ushort h2 = 0, l2 = 0;
    if (lane < 22) { h2 = bf16_rne(a2); l2 = bf16_rne(a2 - bf16f(h2)); }
    Xhi[base + 128 + lane] = h2; Xlo[base + 128 + lane] = l2;
  }
}

// ---------------- fused MFMA GRU ----------------
// 1D grid 7840, XCD-swizzled so the 5 dblk-blocks of one mblk run consecutively
// on the SAME XCD (A-rows hit L2 for 4 of 5 reads). H staged from fp32 hcur and
// split to bf16 hi/lo in-register; epilogue writes fp32 hnext (stride 160).
__global__ __launch_bounds__(256) void gru_mfma_kernel(
    const ushort* __restrict__ Xhi, const ushort* __restrict__ Xlo,
    const float* __restrict__ hcur, const int hstride,
    const ushort* __restrict__ Whi, const ushort* __restrict__ Wlo,
    const float* __restrict__ bih, const float* __restrict__ bhh,
    float* __restrict__ hnext) {
  __shared__ ushort smem[2][8192];  // 2 x 16KB k-buffers; f32 scratch in epilogue
  // XCD-aware swizzle (bijective over 5 x 1568)
  const int flat = blockIdx.x;
  const int xcd = flat & 7;
  const int q = flat >> 3;           // 0..979
  const int dblk = q % 5;
  const int mblk = (q / 5) * 8 + xcd;
  if (mblk >= 1563) return;

  const int tid = threadIdx.x;
  const int w = tid >> 6;
  const int l = tid & 63;
  const int c16 = l & 15;
  const int koct = l >> 4;

  // staging map: thread -> (row sr, octet so); swizzled octet sop
  const int sr = tid >> 2;
  const int so = tid & 3;
  const int sop = so ^ ((sr >> 1) & 3);
  const int gm = mblk * 64 + sr;
  const bool rowok = gm < N_NODES;
  const int g_off = gm * 160 + so * 8;
  const int lds_w_off = sr * 64 + sop * 16;  // bytes; + arr*4096 + buf*16384

  const int hi_b = (w < 2) ? 0 : 2;   // arrays: 0 Xhi, 1 Xlo, 2 Hhi, 3 Hlo
  const int dt = w & 1;
  const int ch0 = (w < 2) ? 0 : 3;
  const int nbase = dblk * 32 + dt * 16 + c16;

  f32x4 acc[3][4];
#pragma unroll
  for (int a = 0; a < 3; ++a)
#pragma unroll
    for (int b = 0; b < 4; ++b) acc[a][b] = (f32x4){0.f, 0.f, 0.f, 0.f};

  auto loadH = [&](int kc, float* hv) {
    const int kb = kc * 32 + so * 8;
    const float* hrow = hcur + (size_t)gm * hstride + kb;
#pragma unroll
    for (int e = 0; e < 8; e += 2) {
      float x0 = 0.f, x1 = 0.f;
      if (rowok) {
        if (kb + e + 1 < HDIM) { float2 v2 = *(const float2*)(hrow + e); x0 = v2.x; x1 = v2.y; }
        else if (kb + e < HDIM) { x0 = hrow[e]; }
      }
      hv[e] = x0; hv[e + 1] = x1;
    }
  };
  auto writeH = [&](int buf, const float* hv) {
    bf16x8 vh, vl;
#pragma unroll
    for (int e = 0; e < 8; ++e) {
      ushort u = bf16_rne(hv[e]);
      vh[e] = (short)u;
      vl[e] = (short)bf16_rne(hv[e] - bf16f(u));
    }
    *(bf16x8*)((char*)smem + buf * 16384 + 2 * 4096 + lds_w_off) = vh;
    *(bf16x8*)((char*)smem + buf * 16384 + 3 * 4096 + lds_w_off) = vl;
  };

  {  // initial stage kc=0
    bf16x8 x0 = *(const bf16x8*)(Xhi + g_off);
    bf16x8 x1 = *(const bf16x8*)(Xlo + g_off);
    float hv[8];
    loadH(0, hv);
    *(bf16x8*)((char*)smem + 0 * 4096 + lds_w_off) = x0;
    *(bf16x8*)((char*)smem + 1 * 4096 + lds_w_off) = x1;
    writeH(0, hv);
  }
  __syncthreads();

#pragma unroll
  for (int kc = 0; kc < 5; ++kc) {
    const int cur = kc & 1;
    bf16x8 nX0, nX1;
    float nhv[8];
    if (kc < 4) {
      nX0 = *(const bf16x8*)(Xhi + g_off + (kc + 1) * 32);
      nX1 = *(const bf16x8*)(Xlo + g_off + (kc + 1) * 32);
      loadH(kc + 1, nhv);
    }
    bf16x8 ahi[4], alo[4];
#pragma unroll
    for (int mt = 0; mt < 4; ++mt) {
      const int r = mt * 16 + c16;
      const int ob = (koct ^ ((r >> 1) & 3)) * 16;
      ahi[mt] = *(const bf16x8*)((char*)smem + cur * 16384 + hi_b * 4096 + r * 64 + ob);
      alo[mt] = *(const bf16x8*)((char*)smem + cur * 16384 + (hi_b + 1) * 4096 + r * 64 + ob);
    }
    bf16x8 bhi[3], blo[3];
#pragma unroll
    for (int cl = 0; cl < 3; ++cl) {
      const int wo = ((ch0 + cl) * 160 + nbase) * 160 + kc * 32 + koct * 8;
      bhi[cl] = *(const bf16x8*)(Whi + wo);
      blo[cl] = *(const bf16x8*)(Wlo + wo);
    }
#pragma unroll
    for (int cl = 0; cl < 3; ++cl)
#pragma unroll
      for (int mt = 0; mt < 4; ++mt)
        acc[cl][mt] = __builtin_amdgcn_mfma_f32_16x16x32_bf16(ahi[mt], bhi[cl], acc[cl][mt], 0, 0, 0);
#pragma unroll
    for (int cl = 0; cl < 3; ++cl)
#pragma unroll
      for (int mt = 0; mt < 4; ++mt)
        acc[cl][mt] = __builtin_amdgcn_mfma_f32_16x16x32_bf16(ahi[mt], blo[cl], acc[cl][mt], 0, 0, 0);
#pragma unroll
    for (int cl = 0; cl < 3; ++cl)
#pragma unroll
      for (int mt = 0; mt < 4; ++mt)
        acc[cl][mt] = __builtin_amdgcn_mfma_f32_16x16x32_bf16(alo[mt], bhi[cl], acc[cl][mt], 0, 0, 0);
    if (kc < 4) {
      const int nb = cur ^ 1;
      *(bf16x8*)((char*)smem + nb * 16384 + 0 * 4096 + lds_w_off) = nX0;
      *(bf16x8*)((char*)smem + nb * 16384 + 1 * 4096 + lds_w_off) = nX1;
      writeH(nb, nhv);
    }
    __syncthreads();
  }

  // epilogue: H-waves publish, X-waves combine + write hnext (stride 160)
  float* eps = (float*)smem;
  if (w >= 2) {
    const int wi = w - 2;
#pragma unroll
    for (int cl = 0; cl < 3; ++cl)
#pragma unroll
      for (int mt = 0; mt < 4; ++mt)
        *(f32x4*)&eps[(((wi * 3 + cl) * 4 + mt) * 64 + l) * 4] = acc[cl][mt];
  }
  __syncthreads();
  if (w < 2) {
    const int d = dblk * 32 + dt * 16 + c16;
    if (d < HDIM) {
      const float bir = bih[d], biz = bih[HDIM + d], bin = bih[2 * HDIM + d];
      const float bhr = bhh[d], bhz = bhh[HDIM + d], bhn = bhh[2 * HDIM + d];
#pragma unroll
      for (int mt = 0; mt < 4; ++mt) {
        const int mb = mblk * 64 + mt * 16 + koct * 4;
        f32x4 hr4 = *(const f32x4*)&eps[(((dt * 3 + 0) * 4 + mt) * 64 + l) * 4];
        f32x4 hz4 = *(const f32x4*)&eps[(((dt * 3 + 1) * 4 + mt) * 64 + l) * 4];
        f32x4 hn4 = *(const f32x4*)&eps[(((dt * 3 + 2) * 4 + mt) * 64 + l) * 4];
#pragma unroll
        for (int j = 0; j < 4; ++j) {
          const int m = mb + j;
          if (m < N_NODES) {
            const float r = 1.f / (1.f + __expf(-(acc[0][mt][j] + bir + hr4[j] + bhr)));
            const float z = 1.f / (1.f + __expf(-(acc[1][mt][j] + biz + hz4[j] + bhz)));
            const float na = acc[2][mt][j] + bin + r * (hn4[j] + bhn);
            const float nn = 1.f - 2.f / (__expf(2.f * na) + 1.f);  // tanh
            const float ho = hcur[(size_t)m * hstride + d];
            hnext[m * 160 + d] = (1.f - z) * nn + z * ho;
          }
        }
      }
    }
  }
}

// ---------------- readout ----------------
__global__ __launch_bounds__(64) void graph_accum_kernel(const float* __restrict__ h,
    const int* __restrict__ gids, float* __restrict__ gacc) {
  const int lane = threadIdx.x;
  const int nb = gridDim.x;
  int chunk = (N_NODES + nb - 1) / nb;
  int b = blockIdx.x * chunk, e = min(b + chunk, N_NODES);
  if (b >= e) return;
  float a0 = 0.f, a1 = 0.f, a2 = 0.f;
  int cur = gids[b];
  for (int i = b; i < e; ++i) {
    int gid = gids[i];
    if (gid != cur) {
      atomicAdd(&gacc[cur * HDIM + lane], a0);
      atomicAdd(&gacc[cur * HDIM + lane + 64], a1);
      if (lane < 22) atomicAdd(&gacc[cur * HDIM + lane + 128], a2);
      a0 = a1 = a2 = 0.f; cur = gid;
    }
    const float* hr = h + (size_t)i * 160;
    a0 += hr[lane]; a1 += hr[lane + 64];
    if (lane < 22) a2 += hr[lane + 128];
  }
  atomicAdd(&gacc[cur * HDIM + lane], a0);
  atomicAdd(&gacc[cur * HDIM + lane + 64], a1);
  if (lane < 22) atomicAdd(&gacc[cur * HDIM + lane + 128], a2);
}

__global__ __launch_bounds__(192) void readout_kernel(const float* __restrict__ gacc,
    const float* __restrict__ fc1w, const float* __restrict__ fc1b,
    const float* __restrict__ fc2w, const float* __restrict__ fc2b,
    const float* __restrict__ fclw, const float* __restrict__ fclb,
    float* __restrict__ out) {
  __shared__ float x0[HDIM];
  __shared__ float y1[80];
  __shared__ float y2[80];
  int g = blockIdx.x, t = threadIdx.x;
  if (t < HDIM) {
    float v = logf(gacc[g * HDIM + t]);
    if (v != v) v = 0.f;
    x0[t] = fmaxf(v, 0.f);
  }
  __syncthreads();
  if (t < 80) {
    float s = fc1b[t];
    for (int k = 0; k < HDIM; ++k) s += x0[k] * fc1w[t * HDIM + k];
    y1[t] = (s > 0.f) ? s : 0.01f * s;
  }
  __syncthreads();
  if (t < 80) {
    float s = fc2b[t];
    for (int k = 0; k < 80; ++k) s += y1[k] * fc2w[t * 80 + k];
    y2[t] = (s > 0.f) ? s : 0.01f * s;
  }
  __syncthreads();
  if (t < 10) {
    float s = fclb[t];
    for (int k = 0; k < 80; ++k) s += y2[k] * fclw[t * 80 + k];
    out[g * 10 + t] = s;
  }
}

// ---------------- launch ----------------
extern "C" void kernel_launch(void* const* d_in, const int* in_sizes, int n_in,
                              void* d_out, int out_size, void* d_ws, size_t ws_size,
                              hipStream_t stream) {
  const float* nodes = (const float*)d_in[0];
  const int* src = (const int*)d_in[1];
  const int* dst = (const int*)d_in[2];
  const int* gids = (const int*)d_in[3];
  const float* wih = (const float*)d_in[4];
  const float* whh = (const float*)d_in[5];
  const float* bih = (const float*)d_in[6];
  const float* bhh = (const float*)d_in[7];
  const float* fc1w = (const float*)d_in[8];
  const float* fc1b = (const float*)d_in[9];
  const float* fc2w = (const float*)d_in[10];
  const float* fc2b = (const float*)d_in[11];
  const float* fclw = (const float*)d_in[12];
  const float* fclb = (const float*)d_in[13];
  float* out = (float*)d_out;

  char* wsp = (char*)d_ws;
  size_t off = 0;
  auto carve = [&](size_t bytes) {
    void* p = wsp + off;
    off += (bytes + 255) & ~(size_t)255;
    return p;
  };
  int* counts   = (int*)carve((size_t)N_NODES * 4);
  int* rowstart = (int*)carve((size_t)(N_NODES + 1) * 4);
  int* cursor   = (int*)carve((size_t)N_NODES * 4);
  int* partials = (int*)carve((size_t)512 * 4);
  int* csr      = (int*)carve((size_t)N_EDGES * 4);
  ushort* Xhi   = (ushort*)carve((size_t)MROWS_PAD * 160 * 2);
  ushort* Xlo   = (ushort*)carve((size_t)MROWS_PAD * 160 * 2);
  float* hA     = (float*)carve((size_t)MROWS_PAD * 160 * 4);
  float* hB     = (float*)carve((size_t)MROWS_PAD * 160 * 4);
  ushort* Whi   = (ushort*)carve((size_t)960 * 160 * 2);
  ushort* Wlo   = (ushort*)carve((size_t)960 * 160 * 2);
  float* gacc   = (float*)carve((size_t)N_GRAPHS * HDIM * 4);
  (void)ws_size; (void)in_sizes; (void)n_in; (void)out_size;

  hipMemsetAsync(counts, 0, (size_t)N_NODES * 4, stream);
  hipMemsetAsync(gacc, 0, (size_t)N_GRAPHS * HDIM * 4, stream);

  hist_kernel<<<(N_EDGES + 255) / 256, 256, 0, stream>>>(dst, counts, N_EDGES);
  scan1_kernel<<<SCAN_NBLK, 256, 0, stream>>>(counts, partials);
  scan2_kernel<<<1, 512, 0, stream>>>(partials, rowstart);
  scan3_kernel<<<SCAN_NBLK, 256, 0, stream>>>(counts, partials, rowstart, cursor);
  fill_kernel<<<(N_EDGES + 255) / 256, 256, 0, stream>>>(src, dst, cursor, csr, N_EDGES);
  wbuild_kernel<<<600, 256, 0, stream>>>(wih, whh, Whi, Wlo);

  const float* hcur = nodes;
  int hstride = HDIM;
  float* hnxt = hA;
  for (int p = 0; p < PASSES; ++p) {
    segsum_kernel<<<25000, 256, 0, stream>>>(hcur, hstride, rowstart, csr, Xhi, Xlo);
    gru_mfma_kernel<<<7840, 256, 0, stream>>>(
        Xhi, Xlo, hcur, hstride, Whi, Wlo, bih, bhh, hnxt);
    hcur = hnxt;
    hstride = 160;
    hnxt = (hnxt == hA) ? hB : hA;
  }
  // final h in hcur (stride 160)

  graph_accum_kernel<<<512, 64, 0, stream>>>(hcur, gids, gacc);
  readout_kernel<<<N_GRAPHS, 192, 0, stream>>>(gacc, fc1w, fc1b, fc2w, fc2b, fclw, fclb, out);
}

// Round 5
// 1555.883 us; speedup vs baseline: 6.1222x; 1.0782x over previous
//
#include <hip/hip_runtime.h>

#define N_NODES 100000
#define N_EDGES 1600000
#define N_GRAPHS 64
#define HDIM 150
#define PASSES 4
#define MROWS_PAD 100032   // 1563 * 64
#define SCAN_NBLK 391      // ceil(100000/256)

typedef __attribute__((ext_vector_type(8))) short bf16x8;
typedef __attribute__((ext_vector_type(4))) float f32x4;

__device__ __forceinline__ ushort bf16_rne(float x) {
  uint u = __float_as_uint(x);
  u += 0x7FFFu + ((u >> 16) & 1u);
  return (ushort)(u >> 16);
}
__device__ __forceinline__ float bf16f(ushort h) { return __uint_as_float(((uint)h) << 16); }

// ---------------- CSR build ----------------
__global__ void hist_kernel(const int* __restrict__ dst, int* __restrict__ counts, int n) {
  int i = blockIdx.x * blockDim.x + threadIdx.x;
  if (i < n) atomicAdd(&counts[dst[i]], 1);
}

// multi-block scan: (1) block partial sums, (2) scan partials, (3) apply
__global__ __launch_bounds__(256) void scan1_kernel(const int* __restrict__ counts,
                                                    int* __restrict__ partials) {
  int i = blockIdx.x * 256 + threadIdx.x;
  int v = (i < N_NODES) ? counts[i] : 0;
#pragma unroll
  for (int o = 32; o; o >>= 1) v += __shfl_down(v, o);
  __shared__ int ws4[4];
  if ((threadIdx.x & 63) == 0) ws4[threadIdx.x >> 6] = v;
  __syncthreads();
  if (threadIdx.x == 0) partials[blockIdx.x] = ws4[0] + ws4[1] + ws4[2] + ws4[3];
}

__global__ __launch_bounds__(512) void scan2_kernel(int* __restrict__ partials,
                                                    int* __restrict__ row_start) {
  __shared__ int s[512];
  int t = threadIdx.x;
  int v = (t < SCAN_NBLK) ? partials[t] : 0;
  s[t] = v;
  __syncthreads();
  for (int o = 1; o < 512; o <<= 1) {
    int u = (t >= o) ? s[t - o] : 0;
    __syncthreads();
    s[t] += u;
    __syncthreads();
  }
  if (t < SCAN_NBLK) partials[t] = s[t] - v;  // exclusive block offsets
  if (t == 0) row_start[N_NODES] = s[511];    // total = N_EDGES
}

__global__ __launch_bounds__(256) void scan3_kernel(const int* __restrict__ counts,
    const int* __restrict__ partials, int* __restrict__ row_start, int* __restrict__ cursor) {
  __shared__ int s[256];
  int t = threadIdx.x, i = blockIdx.x * 256 + t;
  int v = (i < N_NODES) ? counts[i] : 0;
  s[t] = v;
  __syncthreads();
  for (int o = 1; o < 256; o <<= 1) {
    int u = (t >= o) ? s[t - o] : 0;
    __syncthreads();
    s[t] += u;
    __syncthreads();
  }
  if (i < N_NODES) {
    int ex = s[t] - v + partials[blockIdx.x];
    row_start[i] = ex; cursor[i] = ex;
  }
}

__global__ void fill_kernel(const int* __restrict__ src, const int* __restrict__ dst,
                            int* __restrict__ cursor, int* __restrict__ csr_src, int n) {
  int i = blockIdx.x * blockDim.x + threadIdx.x;
  if (i < n) {
    int pos = atomicAdd(&cursor[dst[i]], 1);
    csr_src[pos] = src[i];
  }
}

// ---------------- weight split: Wcat[ch*160+dd][k], 960x160, bf16 hi/lo ----------------
__global__ void wbuild_kernel(const float* __restrict__ wih, const float* __restrict__ whh,
                              ushort* __restrict__ Whi, ushort* __restrict__ Wlo) {
  int idx = blockIdx.x * 256 + threadIdx.x;
  if (idx >= 960 * 160) return;
  int n = idx / 160, k = idx - n * 160;
  int ch = n / 160, dd = n - ch * 160;
  float v = 0.f;
  if (dd < HDIM && k < HDIM)
    v = (ch < 3) ? wih[(ch * HDIM + dd) * HDIM + k] : whh[((ch - 3) * HDIM + dd) * HDIM + k];
  ushort hi = bf16_rne(v);
  ushort lo = bf16_rne(v - bf16f(hi));
  Whi[idx] = hi; Wlo[idx] = lo;
}

// ---------------- segment sum: X[v] = sum h[u] over edges u->v; writes bf16 hi/lo ----------------
// MLP-optimized: lanes cooperatively preload 64 CSR indices (1 coalesced load),
// broadcast via shfl, explicit x4 unroll so ~12 row loads are in flight per wave.
__global__ __launch_bounds__(256) void segsum_kernel(const float* __restrict__ h, const int hstride,
    const int* __restrict__ row_start, const int* __restrict__ csr_src,
    ushort* __restrict__ Xhi, ushort* __restrict__ Xlo) {
  int node = blockIdx.x * 4 + (threadIdx.x >> 6);
  if (node >= N_NODES) return;
  int lane = threadIdx.x & 63;
  int b = row_start[node], e = row_start[node + 1];
  int cnt = e - b;
  float a0 = 0.f, a1 = 0.f, a2 = 0.f;
  const bool l22 = lane < 22;

  for (int base = 0; base < cnt; base += 64) {
    const int nb = min(64, cnt - base);
    int myidx = (base + lane < cnt) ? csr_src[b + base + lane] : 0;
    int jj = 0;
    for (; jj + 4 <= nb; jj += 4) {
      const int s0 = __shfl(myidx, jj);
      const int s1 = __shfl(myidx, jj + 1);
      const int s2 = __shfl(myidx, jj + 2);
      const int s3 = __shfl(myidx, jj + 3);
      const float* r0 = h + (size_t)s0 * hstride;
      const float* r1 = h + (size_t)s1 * hstride;
      const float* r2 = h + (size_t)s2 * hstride;
      const float* r3 = h + (size_t)s3 * hstride;
      // issue all independent loads before accumulating
      float v00 = r0[lane],      v10 = r1[lane],      v20 = r2[lane],      v30 = r3[lane];
      float v01 = r0[lane + 64], v11 = r1[lane + 64], v21 = r2[lane + 64], v31 = r3[lane + 64];
      float v02 = 0.f, v12 = 0.f, v22 = 0.f, v32 = 0.f;
      if (l22) {
        v02 = r0[lane + 128]; v12 = r1[lane + 128];
        v22 = r2[lane + 128]; v32 = r3[lane + 128];
      }
      a0 += (v00 + v10) + (v20 + v30);
      a1 += (v01 + v11) + (v21 + v31);
      a2 += (v02 + v12) + (v22 + v32);
    }
    for (; jj < nb; ++jj) {
      const int s0 = __shfl(myidx, jj);
      const float* r0 = h + (size_t)s0 * hstride;
      a0 += r0[lane];
      a1 += r0[lane + 64];
      if (l22) a2 += r0[lane + 128];
    }
  }

  int basep = node * 160;
  ushort h0 = bf16_rne(a0), l0 = bf16_rne(a0 - bf16f(h0));
  ushort h1 = bf16_rne(a1), l1 = bf16_rne(a1 - bf16f(h1));
  Xhi[basep + lane] = h0; Xlo[basep + lane] = l0;
  Xhi[basep + 64 + lane] = h1; Xlo[basep + 64 + lane] = l1;
  if (lane < 32) {
    ushort h2 = 0, l2 = 0;
    if (l22) { h2 = bf16_rne(a2); l2 = bf16_rne(a2 - bf16f(h2)); }
    Xhi[basep + 128 + lane] = h2; Xlo[basep + 128 + lane] = l2;
  }
}

// ---------------- fused MFMA GRU ----------------
// 1D grid 7840, XCD-swizzled so the 5 dblk-blocks of one mblk run consecutively
// on the SAME XCD (A-rows hit L2 for 4 of 5 reads). H staged from fp32 hcur and
// split to bf16 hi/lo in-register; epilogue writes fp32 hnext (stride 160).
__global__ __launch_bounds__(256) void gru_mfma_kernel(
    const ushort* __restrict__ Xhi, const ushort* __restrict__ Xlo,
    const float* __restrict__ hcur, const int hstride,
    const ushort* __restrict__ Whi, const ushort* __restrict__ Wlo,
    const float* __restrict__ bih, const float* __restrict__ bhh,
    float* __restrict__ hnext) {
  __shared__ ushort smem[2][8192];  // 2 x 16KB k-buffers; f32 scratch in epilogue
  // XCD-aware swizzle (bijective over 5 x 1568)
  const int flat = blockIdx.x;
  const int xcd = flat & 7;
  const int q = flat >> 3;           // 0..979
  const int dblk = q % 5;
  const int mblk = (q / 5) * 8 + xcd;
  if (mblk >= 1563) return;

  const int tid = threadIdx.x;
  const int w = tid >> 6;
  const int l = tid & 63;
  const int c16 = l & 15;
  const int koct = l >> 4;

  // staging map: thread -> (row sr, octet so); swizzled octet sop
  const int sr = tid >> 2;
  const int so = tid & 3;
  const int sop = so ^ ((sr >> 1) & 3);
  const int gm = mblk * 64 + sr;
  const bool rowok = gm < N_NODES;
  const int g_off = gm * 160 + so * 8;
  const int lds_w_off = sr * 64 + sop * 16;  // bytes; + arr*4096 + buf*16384

  const int hi_b = (w < 2) ? 0 : 2;   // arrays: 0 Xhi, 1 Xlo, 2 Hhi, 3 Hlo
  const int dt = w & 1;
  const int ch0 = (w < 2) ? 0 : 3;
  const int nbase = dblk * 32 + dt * 16 + c16;

  f32x4 acc[3][4];
#pragma unroll
  for (int a = 0; a < 3; ++a)
#pragma unroll
    for (int b = 0; b < 4; ++b) acc[a][b] = (f32x4){0.f, 0.f, 0.f, 0.f};

  auto loadH = [&](int kc, float* hv) {
    const int kb = kc * 32 + so * 8;
    const float* hrow = hcur + (size_t)gm * hstride + kb;
#pragma unroll
    for (int e = 0; e < 8; e += 2) {
      float x0 = 0.f, x1 = 0.f;
      if (rowok) {
        if (kb + e + 1 < HDIM) { float2 v2 = *(const float2*)(hrow + e); x0 = v2.x; x1 = v2.y; }
        else if (kb + e < HDIM) { x0 = hrow[e]; }
      }
      hv[e] = x0; hv[e + 1] = x1;
    }
  };
  auto writeH = [&](int buf, const float* hv) {
    bf16x8 vh, vl;
#pragma unroll
    for (int e = 0; e < 8; ++e) {
      ushort u = bf16_rne(hv[e]);
      vh[e] = (short)u;
      vl[e] = (short)bf16_rne(hv[e] - bf16f(u));
    }
    *(bf16x8*)((char*)smem + buf * 16384 + 2 * 4096 + lds_w_off) = vh;
    *(bf16x8*)((char*)smem + buf * 16384 + 3 * 4096 + lds_w_off) = vl;
  };

  {  // initial stage kc=0
    bf16x8 x0 = *(const bf16x8*)(Xhi + g_off);
    bf16x8 x1 = *(const bf16x8*)(Xlo + g_off);
    float hv[8];
    loadH(0, hv);
    *(bf16x8*)((char*)smem + 0 * 4096 + lds_w_off) = x0;
    *(bf16x8*)((char*)smem + 1 * 4096 + lds_w_off) = x1;
    writeH(0, hv);
  }
  __syncthreads();

#pragma unroll
  for (int kc = 0; kc < 5; ++kc) {
    const int cur = kc & 1;
    bf16x8 nX0, nX1;
    float nhv[8];
    if (kc < 4) {
      nX0 = *(const bf16x8*)(Xhi + g_off + (kc + 1) * 32);
      nX1 = *(const bf16x8*)(Xlo + g_off + (kc + 1) * 32);
      loadH(kc + 1, nhv);
    }
    bf16x8 ahi[4], alo[4];
#pragma unroll
    for (int mt = 0; mt < 4; ++mt) {
      const int r = mt * 16 + c16;
      const int ob = (koct ^ ((r >> 1) & 3)) * 16;
      ahi[mt] = *(const bf16x8*)((char*)smem + cur * 16384 + hi_b * 4096 + r * 64 + ob);
      alo[mt] = *(const bf16x8*)((char*)smem + cur * 16384 + (hi_b + 1) * 4096 + r * 64 + ob);
    }
    bf16x8 bhi[3], blo[3];
#pragma unroll
    for (int cl = 0; cl < 3; ++cl) {
      const int wo = ((ch0 + cl) * 160 + nbase) * 160 + kc * 32 + koct * 8;
      bhi[cl] = *(const bf16x8*)(Whi + wo);
      blo[cl] = *(const bf16x8*)(Wlo + wo);
    }
#pragma unroll
    for (int cl = 0; cl < 3; ++cl)
#pragma unroll
      for (int mt = 0; mt < 4; ++mt)
        acc[cl][mt] = __builtin_amdgcn_mfma_f32_16x16x32_bf16(ahi[mt], bhi[cl], acc[cl][mt], 0, 0, 0);
#pragma unroll
    for (int cl = 0; cl < 3; ++cl)
#pragma unroll
      for (int mt = 0; mt < 4; ++mt)
        acc[cl][mt] = __builtin_amdgcn_mfma_f32_16x16x32_bf16(ahi[mt], blo[cl], acc[cl][mt], 0, 0, 0);
#pragma unroll
    for (int cl = 0; cl < 3; ++cl)
#pragma unroll
      for (int mt = 0; mt < 4; ++mt)
        acc[cl][mt] = __builtin_amdgcn_mfma_f32_16x16x32_bf16(alo[mt], bhi[cl], acc[cl][mt], 0, 0, 0);
    if (kc < 4) {
      const int nb = cur ^ 1;
      *(bf16x8*)((char*)smem + nb * 16384 + 0 * 4096 + lds_w_off) = nX0;
      *(bf16x8*)((char*)smem + nb * 16384 + 1 * 4096 + lds_w_off) = nX1;
      writeH(nb, nhv);
    }
    __syncthreads();
  }

  // epilogue: H-waves publish, X-waves combine + write hnext (stride 160)
  float* eps = (float*)smem;
  if (w >= 2) {
    const int wi = w - 2;
#pragma unroll
    for (int cl = 0; cl < 3; ++cl)
#pragma unroll
      for (int mt = 0; mt < 4; ++mt)
        *(f32x4*)&eps[(((wi * 3 + cl) * 4 + mt) * 64 + l) * 4] = acc[cl][mt];
  }
  __syncthreads();
  if (w < 2) {
    const int d = dblk * 32 + dt * 16 + c16;
    if (d < HDIM) {
      const float bir = bih[d], biz = bih[HDIM + d], bin = bih[2 * HDIM + d];
      const float bhr = bhh[d], bhz = bhh[HDIM + d], bhn = bhh[2 * HDIM + d];
#pragma unroll
      for (int mt = 0; mt < 4; ++mt) {
        const int mb = mblk * 64 + mt * 16 + koct * 4;
        f32x4 hr4 = *(const f32x4*)&eps[(((dt * 3 + 0) * 4 + mt) * 64 + l) * 4];
        f32x4 hz4 = *(const f32x4*)&eps[(((dt * 3 + 1) * 4 + mt) * 64 + l) * 4];
        f32x4 hn4 = *(const f32x4*)&eps[(((dt * 3 + 2) * 4 + mt) * 64 + l) * 4];
#pragma unroll
        for (int j = 0; j < 4; ++j) {
          const int m = mb + j;
          if (m < N_NODES) {
            const float r = 1.f / (1.f + __expf(-(acc[0][mt][j] + bir + hr4[j] + bhr)));
            const float z = 1.f / (1.f + __expf(-(acc[1][mt][j] + biz + hz4[j] + bhz)));
            const float na = acc[2][mt][j] + bin + r * (hn4[j] + bhn);
            const float nn = 1.f - 2.f / (__expf(2.f * na) + 1.f);  // tanh
            const float ho = hcur[(size_t)m * hstride + d];
            hnext[m * 160 + d] = (1.f - z) * nn + z * ho;
          }
        }
      }
    }
  }
}

// ---------------- readout ----------------
__global__ __launch_bounds__(64) void graph_accum_kernel(const float* __restrict__ h,
    const int* __restrict__ gids, float* __restrict__ gacc) {
  const int lane = threadIdx.x;
  const int nb = gridDim.x;
  int chunk = (N_NODES + nb - 1) / nb;
  int b = blockIdx.x * chunk, e = min(b + chunk, N_NODES);
  if (b >= e) return;
  float a0 = 0.f, a1 = 0.f, a2 = 0.f;
  int cur = gids[b];
  for (int i = b; i < e; ++i) {
    int gid = gids[i];
    if (gid != cur) {
      atomicAdd(&gacc[cur * HDIM + lane], a0);
      atomicAdd(&gacc[cur * HDIM + lane + 64], a1);
      if (lane < 22) atomicAdd(&gacc[cur * HDIM + lane + 128], a2);
      a0 = a1 = a2 = 0.f; cur = gid;
    }
    const float* hr = h + (size_t)i * 160;
    a0 += hr[lane]; a1 += hr[lane + 64];
    if (lane < 22) a2 += hr[lane + 128];
  }
  atomicAdd(&gacc[cur * HDIM + lane], a0);
  atomicAdd(&gacc[cur * HDIM + lane + 64], a1);
  if (lane < 22) atomicAdd(&gacc[cur * HDIM + lane + 128], a2);
}

__global__ __launch_bounds__(192) void readout_kernel(const float* __restrict__ gacc,
    const float* __restrict__ fc1w, const float* __restrict__ fc1b,
    const float* __restrict__ fc2w, const float* __restrict__ fc2b,
    const float* __restrict__ fclw, const float* __restrict__ fclb,
    float* __restrict__ out) {
  __shared__ float x0[HDIM];
  __shared__ float y1[80];
  __shared__ float y2[80];
  int g = blockIdx.x, t = threadIdx.x;
  if (t < HDIM) {
    float v = logf(gacc[g * HDIM + t]);
    if (v != v) v = 0.f;
    x0[t] = fmaxf(v, 0.f);
  }
  __syncthreads();
  if (t < 80) {
    float s = fc1b[t];
    for (int k = 0; k < HDIM; ++k) s += x0[k] * fc1w[t * HDIM + k];
    y1[t] = (s > 0.f) ? s : 0.01f * s;
  }
  __syncthreads();
  if (t < 80) {
    float s = fc2b[t];
    for (int k = 0; k < 80; ++k) s += y1[k] * fc2w[t * 80 + k];
    y2[t] = (s > 0.f) ? s : 0.01f * s;
  }
  __syncthreads();
  if (t < 10) {
    float s = fclb[t];
    for (int k = 0; k < 80; ++k) s += y2[k] * fclw[t * 80 + k];
    out[g * 10 + t] = s;
  }
}

// ---------------- launch ----------------
extern "C" void kernel_launch(void* const* d_in, const int* in_sizes, int n_in,
                              void* d_out, int out_size, void* d_ws, size_t ws_size,
                              hipStream_t stream) {
  const float* nodes = (const float*)d_in[0];
  const int* src = (const int*)d_in[1];
  const int* dst = (const int*)d_in[2];
  const int* gids = (const int*)d_in[3];
  const float* wih = (const float*)d_in[4];
  const float* whh = (const float*)d_in[5];
  const float* bih = (const float*)d_in[6];
  const float* bhh = (const float*)d_in[7];
  const float* fc1w = (const float*)d_in[8];
  const float* fc1b = (const float*)d_in[9];
  const float* fc2w = (const float*)d_in[10];
  const float* fc2b = (const float*)d_in[11];
  const float* fclw = (const float*)d_in[12];
  const float* fclb = (const float*)d_in[13];
  float* out = (float*)d_out;

  char* wsp = (char*)d_ws;
  size_t off = 0;
  auto carve = [&](size_t bytes) {
    void* p = wsp + off;
    off += (bytes + 255) & ~(size_t)255;
    return p;
  };
  int* counts   = (int*)carve((size_t)N_NODES * 4);
  int* rowstart = (int*)carve((size_t)(N_NODES + 1) * 4);
  int* cursor   = (int*)carve((size_t)N_NODES * 4);
  int* partials = (int*)carve((size_t)512 * 4);
  int* csr      = (int*)carve((size_t)N_EDGES * 4);
  ushort* Xhi   = (ushort*)carve((size_t)MROWS_PAD * 160 * 2);
  ushort* Xlo   = (ushort*)carve((size_t)MROWS_PAD * 160 * 2);
  float* hA     = (float*)carve((size_t)MROWS_PAD * 160 * 4);
  float* hB     = (float*)carve((size_t)MROWS_PAD * 160 * 4);
  ushort* Whi   = (ushort*)carve((size_t)960 * 160 * 2);
  ushort* Wlo   = (ushort*)carve((size_t)960 * 160 * 2);
  float* gacc   = (float*)carve((size_t)N_GRAPHS * HDIM * 4);
  (void)ws_size; (void)in_sizes; (void)n_in; (void)out_size;

  hipMemsetAsync(counts, 0, (size_t)N_NODES * 4, stream);
  hipMemsetAsync(gacc, 0, (size_t)N_GRAPHS * HDIM * 4, stream);

  hist_kernel<<<(N_EDGES + 255) / 256, 256, 0, stream>>>(dst, counts, N_EDGES);
  scan1_kernel<<<SCAN_NBLK, 256, 0, stream>>>(counts, partials);
  scan2_kernel<<<1, 512, 0, stream>>>(partials, rowstart);
  scan3_kernel<<<SCAN_NBLK, 256, 0, stream>>>(counts, partials, rowstart, cursor);
  fill_kernel<<<(N_EDGES + 255) / 256, 256, 0, stream>>>(src, dst, cursor, csr, N_EDGES);
  wbuild_kernel<<<600, 256, 0, stream>>>(wih, whh, Whi, Wlo);

  const float* hcur = nodes;
  int hstride = HDIM;
  float* hnxt = hA;
  for (int p = 0; p < PASSES; ++p) {
    segsum_kernel<<<25000, 256, 0, stream>>>(hcur, hstride, rowstart, csr, Xhi, Xlo);
    gru_mfma_kernel<<<7840, 256, 0, stream>>>(
        Xhi, Xlo, hcur, hstride, Whi, Wlo, bih, bhh, hnxt);
    hcur = hnxt;
    hstride = 160;
    hnxt = (hnxt == hA) ? hB : hA;
  }
  // final h in hcur (stride 160)

  graph_accum_kernel<<<512, 64, 0, stream>>>(hcur, gids, gacc);
  readout_kernel<<<N_GRAPHS, 192, 0, stream>>>(gacc, fc1w, fc1b, fc2w, fc2b, fclw, fclb, out);
}